// Round 2
// baseline (2464.384 us; speedup 1.0000x reference)
//
#include <hip/hip_runtime.h>
#include <hip/hip_bf16.h>
#include <stdint.h>

// ---------------------------------------------------------------------------
// AngularAwareTemporalAttention (MI355X / gfx950)
// Pipeline: qkv GEMM (bf16 3-term split MFMA) -> fp32 attention w/ angular
// bias -> proj GEMM (bf16 3-term split MFMA).
// Heads processed in 4 groups of 4 so Q/K/V scratch (96 MB fp32) lives in
// d_out (dead until proj). Workspace-adaptive: plan A pre-splits x to bf16
// hi/lo (needs ~285 MB ws), plan B fuses the split into GEMM staging (~151 MB).
// ---------------------------------------------------------------------------

typedef float f32x4 __attribute__((ext_vector_type(4)));
typedef __bf16 bf16x8 __attribute__((ext_vector_type(8)));
typedef unsigned short us8 __attribute__((ext_vector_type(8)));

#define MROWS 32768  // BN*T = 256*128

static __device__ __forceinline__ unsigned short bfbits(float f) {
  __bf16 h = (__bf16)f;
  return __builtin_bit_cast(unsigned short, h);
}
static __device__ __forceinline__ float bff(unsigned short u) {
  return (float)__builtin_bit_cast(__bf16, u);
}
static __device__ __forceinline__ void gld16(const void* g, void* l) {
  __builtin_amdgcn_global_load_lds(
      (const __attribute__((address_space(1))) void*)g,
      (__attribute__((address_space(3))) void*)l, 16, 0, 0);
}

// fp32 -> bf16 hi/lo split of x (plan A only)
__global__ __launch_bounds__(256) void k_split(const float* __restrict__ x,
                                               unsigned short* __restrict__ xh,
                                               unsigned short* __restrict__ xl,
                                               int n4) {
  int i = blockIdx.x * 256 + threadIdx.x;
  if (i >= n4) return;
  float4 v = ((const float4*)x)[i];
  ushort4 h, l;
  h.x = bfbits(v.x); l.x = bfbits(v.x - bff(h.x));
  h.y = bfbits(v.y); l.y = bfbits(v.y - bff(h.y));
  h.z = bfbits(v.z); l.z = bfbits(v.z - bff(h.z));
  h.w = bfbits(v.w); l.w = bfbits(v.w - bff(h.w));
  ((ushort4*)xh)[i] = h;
  ((ushort4*)xl)[i] = l;
}

// transpose W (K x N) -> (N x K) hi/lo bf16; remap=1 groups qkv cols so that
// group g (heads 4g..4g+3) occupies contiguous rows [g*768, (g+1)*768).
__global__ void k_tsplit(const float* __restrict__ w,
                         unsigned short* __restrict__ th,
                         unsigned short* __restrict__ tl_, int K, int N,
                         int remap) {
  __shared__ float tile[32][33];
  int n0 = blockIdx.x * 32, k0 = blockIdx.y * 32;
  int tx = threadIdx.x, ty = threadIdx.y;
#pragma unroll
  for (int j = 0; j < 32; j += 8)
    tile[ty + j][tx] = w[(size_t)(k0 + ty + j) * N + n0 + tx];
  __syncthreads();
#pragma unroll
  for (int j = 0; j < 32; j += 8) {
    float v = tile[tx][ty + j];
    int n = n0 + ty + j;
    int orow = n;
    if (remap) {
      int s = n >> 10, hid = n & 1023;
      orow = (hid >> 8) * 768 + s * 256 + (hid & 255);
    }
    size_t o = (size_t)orow * K + k0 + tx;
    unsigned short hb = bfbits(v);
    th[o] = hb;
    tl_[o] = bfbits(v - bff(hb));
  }
}

// qkv bias remapped into grouped order
__global__ void k_gbias(const float* __restrict__ b, float* __restrict__ gb) {
  int n = blockIdx.x * 256 + threadIdx.x;
  if (n >= 3072) return;
  int s = n >> 10, hid = n & 1023;
  gb[(hid >> 8) * 768 + s * 256 + (hid & 255)] = b[n];
}

// angular cosine bias (B=4, T=128) -> (4,128,128)
__global__ void k_cos(const float* __restrict__ bv, float* __restrict__ cosb) {
  int b = blockIdx.x, t = threadIdx.x;
  __shared__ float nb[128][3];
  float x = bv[(b * 128 + t) * 3 + 0];
  float y = bv[(b * 128 + t) * 3 + 1];
  float z = bv[(b * 128 + t) * 3 + 2];
  float inv = 1.0f / (sqrtf(x * x + y * y + z * z) + 1e-6f);
  nb[t][0] = x * inv; nb[t][1] = y * inv; nb[t][2] = z * inv;
  __syncthreads();
  float xn = nb[t][0], yn = nb[t][1], zn = nb[t][2];
  for (int j = 0; j < 128; j++) {
    float c = xn * nb[j][0] + yn * nb[j][1] + zn * nb[j][2];
    c = fminf(1.0f, fmaxf(-1.0f, c));
    cosb[((size_t)b * 128 + t) * 128 + j] = c;
  }
}

// ---------------------------------------------------------------------------
// split-bf16 MFMA GEMM, 128x128 tile, BK=32, K=1024.
// AMODE 0: A pre-split bf16 hi/lo (gld16 staging). AMODE 1: A fp32, explicit
// load + in-register hi/lo split at staging (same LDS layout).
// B: pre-split bf16 hi/lo, transposed (rows = output cols), gld16 staging.
// MODE 0: scatter C into q/k/v group buffers (BN,4,T,64). MODE 1: row-major.
// ---------------------------------------------------------------------------
template <int AMODE, int MODE>
__global__ __launch_bounds__(256) void k_gemm(
    const unsigned short* __restrict__ Ah, const unsigned short* __restrict__ Al,
    const float* __restrict__ Af,
    const unsigned short* __restrict__ Bh, const unsigned short* __restrict__ Bl,
    const float* __restrict__ bias, float* __restrict__ C) {
  constexpr int K = 1024;
  __shared__ unsigned short sAh[128 * 32];
  __shared__ unsigned short sAl[128 * 32];
  __shared__ unsigned short sBh[128 * 32];
  __shared__ unsigned short sBl[128 * 32];
  int tid = threadIdx.x;
  int wave = tid >> 6, lane = tid & 63;
  int rowBase = blockIdx.x * 128, colBase = blockIdx.y * 128;
  int wm = wave & 1, wn = wave >> 1;
  int fr = lane & 15, fq = lane >> 4;

  f32x4 acc[4][4];
#pragma unroll
  for (int i = 0; i < 4; i++)
#pragma unroll
    for (int j = 0; j < 4; j++) acc[i][j] = (f32x4){0.f, 0.f, 0.f, 0.f};

  int srow = tid >> 2, scol = (tid & 3) * 8;
  const unsigned short* Bbase = Bh + (size_t)(colBase + srow) * K + scol;
  const unsigned short* Blbase = Bl + (size_t)(colBase + srow) * K + scol;
  const unsigned short* Abase = Ah + (size_t)(rowBase + srow) * K + scol;
  const unsigned short* Albase = Al + (size_t)(rowBase + srow) * K + scol;
  const float* Afbase = Af + (size_t)(rowBase + srow) * K + scol;
  const size_t rstep = (size_t)64 * K;

  for (int kk = 0; kk < K; kk += 32) {
    __syncthreads();  // prior compute done before LDS overwrite
#pragma unroll
    for (int p = 0; p < 2; p++) {
      gld16(Bbase + p * rstep + kk, sBh + p * 2048 + wave * 512);
      gld16(Blbase + p * rstep + kk, sBl + p * 2048 + wave * 512);
    }
    if constexpr (AMODE == 0) {
#pragma unroll
      for (int p = 0; p < 2; p++) {
        gld16(Abase + p * rstep + kk, sAh + p * 2048 + wave * 512);
        gld16(Albase + p * rstep + kk, sAl + p * 2048 + wave * 512);
      }
    } else {
#pragma unroll
      for (int p = 0; p < 2; p++) {
        float4 v0 = *(const float4*)(Afbase + p * rstep + kk);
        float4 v1 = *(const float4*)(Afbase + p * rstep + kk + 4);
        float vv[8] = {v0.x, v0.y, v0.z, v0.w, v1.x, v1.y, v1.z, v1.w};
        us8 hv, lv;
#pragma unroll
        for (int i = 0; i < 8; i++) {
          unsigned short hb = bfbits(vv[i]);
          hv[i] = hb;
          lv[i] = bfbits(vv[i] - bff(hb));
        }
        *(us8*)(sAh + p * 2048 + tid * 8) = hv;  // (p*64+srow)*32 + scol
        *(us8*)(sAl + p * 2048 + tid * 8) = lv;
      }
    }
    __syncthreads();  // drains gld16 vmcnt + ds_writes

    bf16x8 fah[4], fal[4], fbh[4], fbl[4];
#pragma unroll
    for (int mi = 0; mi < 4; mi++) {
      int r = wm * 64 + mi * 16 + fr;
      fah[mi] = *(const bf16x8*)(sAh + r * 32 + fq * 8);
      fal[mi] = *(const bf16x8*)(sAl + r * 32 + fq * 8);
    }
#pragma unroll
    for (int ni = 0; ni < 4; ni++) {
      int c = wn * 64 + ni * 16 + fr;
      fbh[ni] = *(const bf16x8*)(sBh + c * 32 + fq * 8);
      fbl[ni] = *(const bf16x8*)(sBl + c * 32 + fq * 8);
    }
#pragma unroll
    for (int mi = 0; mi < 4; mi++)
#pragma unroll
      for (int ni = 0; ni < 4; ni++) {
        acc[mi][ni] = __builtin_amdgcn_mfma_f32_16x16x32_bf16(
            fah[mi], fbh[ni], acc[mi][ni], 0, 0, 0);
        acc[mi][ni] = __builtin_amdgcn_mfma_f32_16x16x32_bf16(
            fah[mi], fbl[ni], acc[mi][ni], 0, 0, 0);
        acc[mi][ni] = __builtin_amdgcn_mfma_f32_16x16x32_bf16(
            fal[mi], fbh[ni], acc[mi][ni], 0, 0, 0);
      }
  }

  // C/D layout: row = quad*4 + reg, col = lane&15 (verified m89/m91)
#pragma unroll
  for (int mi = 0; mi < 4; mi++)
#pragma unroll
    for (int ni = 0; ni < 4; ni++)
#pragma unroll
      for (int rr = 0; rr < 4; rr++) {
        int row = rowBase + wm * 64 + mi * 16 + fq * 4 + rr;
        int col = colBase + wn * 64 + ni * 16 + fr;
        float v = acc[mi][ni][rr] + bias[col];
        if constexpr (MODE == 0) {
          int s = col >> 8, hl = (col >> 6) & 3, d = col & 63;
          int bn = row >> 7, t = row & 127;
          C[(size_t)s * 8388608 + ((size_t)(bn * 4 + hl) * 128 + t) * 64 + d] = v;
        } else {
          C[(size_t)row * 1024 + col] = v;
        }
      }
}

// ---------------------------------------------------------------------------
// attention for one head-group g: blocks = BN*4heads*2halves = 2048.
// fp32 exact. LDS: Q 16K + K-tile 16K + S 32K = 64 KB.
// ---------------------------------------------------------------------------
__global__ __launch_bounds__(256) void k_attn(
    const float* __restrict__ Q, const float* __restrict__ Kb,
    const float* __restrict__ V, const float* __restrict__ cosb,
    const float* __restrict__ absSp, unsigned short* __restrict__ Oh,
    unsigned short* __restrict__ Ol, int g) {
  __shared__ __align__(16) float sQ[64 * 64];
  __shared__ __align__(16) float sK[64 * 64];
  __shared__ __align__(16) float sS[64 * 128];

  int bx = blockIdx.x;
  int half = bx & 1;
  int hl = (bx >> 1) & 3;
  int bn = bx >> 3;
  int b = bn >> 6;
  int tid = threadIdx.x, wave = tid >> 6, lane = tid & 63;
  size_t base = ((size_t)(bn * 4 + hl)) * 8192;  // (BN,4,T=128,64)
  float absS = absSp[0];

  {
    const float* src = Q + base + (size_t)half * 4096;
#pragma unroll
    for (int p = 0; p < 4; p++)
      gld16(src + p * 1024 + tid * 4, sQ + p * 1024 + wave * 256);
  }

#pragma unroll
  for (int kt = 0; kt < 2; kt++) {
    __syncthreads();
    {
      const float* src = Kb + base + (size_t)kt * 4096;
#pragma unroll
      for (int p = 0; p < 4; p++)
        gld16(src + p * 1024 + tid * 4, sK + p * 1024 + wave * 256);
    }
    __syncthreads();
    float kreg[64];
#pragma unroll
    for (int i = 0; i < 16; i++) {
      float4 kv = *(const float4*)(sK + lane * 64 + 4 * i);
      kreg[4 * i] = kv.x; kreg[4 * i + 1] = kv.y;
      kreg[4 * i + 2] = kv.z; kreg[4 * i + 3] = kv.w;
    }
#pragma unroll 4
    for (int r = 0; r < 16; r++) {
      int tl = wave * 16 + r;
      float s = 0.f;
#pragma unroll
      for (int i = 0; i < 16; i++) {
        float4 q4 = *(const float4*)(sQ + tl * 64 + 4 * i);
        s = fmaf(q4.x, kreg[4 * i], s);
        s = fmaf(q4.y, kreg[4 * i + 1], s);
        s = fmaf(q4.z, kreg[4 * i + 2], s);
        s = fmaf(q4.w, kreg[4 * i + 3], s);
      }
      int tg = half * 64 + tl;
      float cv = cosb[((size_t)(b * 128 + tg)) * 128 + kt * 64 + lane];
      sS[tl * 128 + kt * 64 + lane] = s * 0.125f + absS * cv;
    }
  }
  __syncthreads();

  for (int r = 0; r < 16; r++) {
    int tl = wave * 16 + r;
    float s0 = sS[tl * 128 + lane], s1 = sS[tl * 128 + 64 + lane];
    float m = fmaxf(s0, s1);
#pragma unroll
    for (int off = 32; off >= 1; off >>= 1) m = fmaxf(m, __shfl_xor(m, off));
    float p0 = __expf(s0 - m), p1 = __expf(s1 - m);
    float sum = p0 + p1;
#pragma unroll
    for (int off = 32; off >= 1; off >>= 1) sum += __shfl_xor(sum, off);
    float inv = 1.0f / sum;
    sS[tl * 128 + lane] = p0 * inv;
    sS[tl * 128 + 64 + lane] = p1 * inv;
  }
  __syncthreads();

  float vreg[128];
#pragma unroll
  for (int j = 0; j < 128; j++) vreg[j] = V[base + j * 64 + lane];
  int hg = g * 4 + hl;
#pragma unroll 4
  for (int r = 0; r < 16; r++) {
    int tl = wave * 16 + r;
    float acc = 0.f;
#pragma unroll
    for (int i = 0; i < 32; i++) {
      float4 p4 = *(const float4*)(sS + tl * 128 + 4 * i);
      acc = fmaf(p4.x, vreg[4 * i], acc);
      acc = fmaf(p4.y, vreg[4 * i + 1], acc);
      acc = fmaf(p4.z, vreg[4 * i + 2], acc);
      acc = fmaf(p4.w, vreg[4 * i + 3], acc);
    }
    int tg = half * 64 + tl;
    size_t off = ((size_t)(bn * 128 + tg)) * 1024 + hg * 64 + lane;
    unsigned short hv = bfbits(acc);
    Oh[off] = hv;
    Ol[off] = bfbits(acc - bff(hv));
  }
}

// ---------------------------------------------------------------------------
extern "C" void kernel_launch(void* const* d_in, const int* in_sizes, int n_in,
                              void* d_out, int out_size, void* d_ws,
                              size_t ws_size, hipStream_t stream) {
  const float* x = (const float*)d_in[0];
  const float* bv = (const float*)d_in[1];
  const float* qkvw = (const float*)d_in[2];
  const float* qkvb = (const float*)d_in[3];
  const float* projw = (const float*)d_in[4];
  const float* projb = (const float*)d_in[5];
  const float* absS = (const float*)d_in[6];
  float* out = (float*)d_out;

  char* ws = (char*)d_ws;
  size_t off = 0;
  auto alloc = [&](size_t b) {
    char* p = ws + off;
    off += (b + 255) & ~(size_t)255;
    return p;
  };
  unsigned short* wqh = (unsigned short*)alloc((size_t)3072 * 1024 * 2);
  unsigned short* wql = (unsigned short*)alloc((size_t)3072 * 1024 * 2);
  unsigned short* wph = (unsigned short*)alloc((size_t)1024 * 1024 * 2);
  unsigned short* wpl = (unsigned short*)alloc((size_t)1024 * 1024 * 2);
  float* gbias = (float*)alloc(3072 * 4);
  float* cosb = (float*)alloc((size_t)4 * 128 * 128 * 4);
  unsigned short* Oh = (unsigned short*)alloc((size_t)MROWS * 1024 * 2);
  unsigned short* Ol = (unsigned short*)alloc((size_t)MROWS * 1024 * 2);
  unsigned short* xh = (unsigned short*)alloc((size_t)MROWS * 1024 * 2);
  unsigned short* xl = (unsigned short*)alloc((size_t)MROWS * 1024 * 2);
  bool planA = (off <= ws_size);  // ws_size constant per session -> same work

  // q/k/v group scratch lives in d_out (dead until proj): 96 MB of 128 MB
  float* qg = (float*)d_out;  // strides: q +0, k +8388608, v +16777216 floats

  k_tsplit<<<dim3(96, 32), dim3(32, 8), 0, stream>>>(qkvw, wqh, wql, 1024, 3072, 1);
  k_tsplit<<<dim3(32, 32), dim3(32, 8), 0, stream>>>(projw, wph, wpl, 1024, 1024, 0);
  k_gbias<<<dim3(12), dim3(256), 0, stream>>>(qkvb, gbias);
  k_cos<<<dim3(4), dim3(128), 0, stream>>>(bv, cosb);
  if (planA)
    k_split<<<dim3(32768), dim3(256), 0, stream>>>(x, xh, xl, 8388608);

  for (int g = 0; g < 4; g++) {
    const unsigned short* bq = wqh + (size_t)g * 768 * 1024;
    const unsigned short* bl = wql + (size_t)g * 768 * 1024;
    if (planA)
      k_gemm<0, 0><<<dim3(256, 6), dim3(256), 0, stream>>>(
          xh, xl, nullptr, bq, bl, gbias + g * 768, qg);
    else
      k_gemm<1, 0><<<dim3(256, 6), dim3(256), 0, stream>>>(
          nullptr, nullptr, x, bq, bl, gbias + g * 768, qg);
    k_attn<<<dim3(2048), dim3(256), 0, stream>>>(
        qg, qg + 8388608, qg + 16777216, cosb, absS, Oh, Ol, g);
  }

  k_gemm<0, 1><<<dim3(256, 8), dim3(256), 0, stream>>>(
      Oh, Ol, nullptr, wph, wpl, projb, out);
}

// Round 3
// 1452.953 us; speedup vs baseline: 1.6961x; 1.6961x over previous
//
#include <hip/hip_runtime.h>
#include <hip/hip_bf16.h>
#include <stdint.h>

// ---------------------------------------------------------------------------
// AngularAwareTemporalAttention (MI355X / gfx950)
// qkv GEMM (bf16 3-term split MFMA, V written transposed) ->
// MFMA attention (bf16 3-term split QK^T and PV, fp32 softmax) ->
// proj GEMM (bf16 3-term split MFMA).
// Heads in 4 groups of 4; Q/K/V group scratch lives in d_out (dead til proj).
// ---------------------------------------------------------------------------

typedef float f32x4 __attribute__((ext_vector_type(4)));
typedef __bf16 bf16x8 __attribute__((ext_vector_type(8)));
typedef unsigned short us8 __attribute__((ext_vector_type(8)));

#define MROWS 32768  // BN*T = 256*128

static __device__ __forceinline__ unsigned short bfbits(float f) {
  __bf16 h = (__bf16)f;
  return __builtin_bit_cast(unsigned short, h);
}
static __device__ __forceinline__ float bff(unsigned short u) {
  return (float)__builtin_bit_cast(__bf16, u);
}
static __device__ __forceinline__ void gld16(const void* g, void* l) {
  __builtin_amdgcn_global_load_lds(
      (const __attribute__((address_space(1))) void*)g,
      (__attribute__((address_space(3))) void*)l, 16, 0, 0);
}
static __device__ __forceinline__ f32x4 mfma16(bf16x8 a, bf16x8 b, f32x4 c) {
  return __builtin_amdgcn_mfma_f32_16x16x32_bf16(a, b, c, 0, 0, 0);
}

// fp32 -> bf16 hi/lo split of x (plan A only)
__global__ __launch_bounds__(256) void k_split(const float* __restrict__ x,
                                               unsigned short* __restrict__ xh,
                                               unsigned short* __restrict__ xl,
                                               int n4) {
  int i = blockIdx.x * 256 + threadIdx.x;
  if (i >= n4) return;
  float4 v = ((const float4*)x)[i];
  ushort4 h, l;
  h.x = bfbits(v.x); l.x = bfbits(v.x - bff(h.x));
  h.y = bfbits(v.y); l.y = bfbits(v.y - bff(h.y));
  h.z = bfbits(v.z); l.z = bfbits(v.z - bff(h.z));
  h.w = bfbits(v.w); l.w = bfbits(v.w - bff(h.w));
  ((ushort4*)xh)[i] = h;
  ((ushort4*)xl)[i] = l;
}

// transpose W (K x N) -> (N x K) hi/lo bf16; remap=1 groups qkv cols so group
// g (heads 4g..4g+3) occupies contiguous rows [g*768,(g+1)*768)
__global__ void k_tsplit(const float* __restrict__ w,
                         unsigned short* __restrict__ th,
                         unsigned short* __restrict__ tl_, int K, int N,
                         int remap) {
  __shared__ float tile[32][33];
  int n0 = blockIdx.x * 32, k0 = blockIdx.y * 32;
  int tx = threadIdx.x, ty = threadIdx.y;
#pragma unroll
  for (int j = 0; j < 32; j += 8)
    tile[ty + j][tx] = w[(size_t)(k0 + ty + j) * N + n0 + tx];
  __syncthreads();
#pragma unroll
  for (int j = 0; j < 32; j += 8) {
    float v = tile[tx][ty + j];
    int n = n0 + ty + j;
    int orow = n;
    if (remap) {
      int s = n >> 10, hid = n & 1023;
      orow = (hid >> 8) * 768 + s * 256 + (hid & 255);
    }
    size_t o = (size_t)orow * K + k0 + tx;
    unsigned short hb = bfbits(v);
    th[o] = hb;
    tl_[o] = bfbits(v - bff(hb));
  }
}

__global__ void k_gbias(const float* __restrict__ b, float* __restrict__ gb) {
  int n = blockIdx.x * 256 + threadIdx.x;
  if (n >= 3072) return;
  int s = n >> 10, hid = n & 1023;
  gb[(hid >> 8) * 768 + s * 256 + (hid & 255)] = b[n];
}

__global__ void k_cos(const float* __restrict__ bv, float* __restrict__ cosb) {
  int b = blockIdx.x, t = threadIdx.x;
  __shared__ float nb[128][3];
  float x = bv[(b * 128 + t) * 3 + 0];
  float y = bv[(b * 128 + t) * 3 + 1];
  float z = bv[(b * 128 + t) * 3 + 2];
  float inv = 1.0f / (sqrtf(x * x + y * y + z * z) + 1e-6f);
  nb[t][0] = x * inv; nb[t][1] = y * inv; nb[t][2] = z * inv;
  __syncthreads();
  float xn = nb[t][0], yn = nb[t][1], zn = nb[t][2];
  for (int j = 0; j < 128; j++) {
    float c = xn * nb[j][0] + yn * nb[j][1] + zn * nb[j][2];
    c = fminf(1.0f, fmaxf(-1.0f, c));
    cosb[((size_t)b * 128 + t) * 128 + j] = c;
  }
}

// ---------------------------------------------------------------------------
// split-bf16 MFMA GEMM, 128x128 tile, BK=32, K=1024. See round-1 comments.
// MODE 0 scatter: q [t][d], k [t][d], v TRANSPOSED [d][t] per (bn,head) tile.
// ---------------------------------------------------------------------------
template <int AMODE, int MODE>
__global__ __launch_bounds__(256) void k_gemm(
    const unsigned short* __restrict__ Ah, const unsigned short* __restrict__ Al,
    const float* __restrict__ Af,
    const unsigned short* __restrict__ Bh, const unsigned short* __restrict__ Bl,
    const float* __restrict__ bias, float* __restrict__ C) {
  constexpr int K = 1024;
  __shared__ unsigned short sAh[128 * 32];
  __shared__ unsigned short sAl[128 * 32];
  __shared__ unsigned short sBh[128 * 32];
  __shared__ unsigned short sBl[128 * 32];
  int tid = threadIdx.x;
  int wave = tid >> 6, lane = tid & 63;
  int rowBase = blockIdx.x * 128, colBase = blockIdx.y * 128;
  int wm = wave & 1, wn = wave >> 1;
  int fr = lane & 15, fq = lane >> 4;

  f32x4 acc[4][4];
#pragma unroll
  for (int i = 0; i < 4; i++)
#pragma unroll
    for (int j = 0; j < 4; j++) acc[i][j] = (f32x4){0.f, 0.f, 0.f, 0.f};

  int srow = tid >> 2, scol = (tid & 3) * 8;
  const unsigned short* Bbase = Bh + (size_t)(colBase + srow) * K + scol;
  const unsigned short* Blbase = Bl + (size_t)(colBase + srow) * K + scol;
  const unsigned short* Abase = Ah + (size_t)(rowBase + srow) * K + scol;
  const unsigned short* Albase = Al + (size_t)(rowBase + srow) * K + scol;
  const float* Afbase = Af + (size_t)(rowBase + srow) * K + scol;
  const size_t rstep = (size_t)64 * K;

  for (int kk = 0; kk < K; kk += 32) {
    __syncthreads();
#pragma unroll
    for (int p = 0; p < 2; p++) {
      gld16(Bbase + p * rstep + kk, sBh + p * 2048 + wave * 512);
      gld16(Blbase + p * rstep + kk, sBl + p * 2048 + wave * 512);
    }
    if constexpr (AMODE == 0) {
#pragma unroll
      for (int p = 0; p < 2; p++) {
        gld16(Abase + p * rstep + kk, sAh + p * 2048 + wave * 512);
        gld16(Albase + p * rstep + kk, sAl + p * 2048 + wave * 512);
      }
    } else {
#pragma unroll
      for (int p = 0; p < 2; p++) {
        float4 v0 = *(const float4*)(Afbase + p * rstep + kk);
        float4 v1 = *(const float4*)(Afbase + p * rstep + kk + 4);
        float vv[8] = {v0.x, v0.y, v0.z, v0.w, v1.x, v1.y, v1.z, v1.w};
        us8 hv, lv;
#pragma unroll
        for (int i = 0; i < 8; i++) {
          unsigned short hb = bfbits(vv[i]);
          hv[i] = hb;
          lv[i] = bfbits(vv[i] - bff(hb));
        }
        *(us8*)(sAh + p * 2048 + tid * 8) = hv;
        *(us8*)(sAl + p * 2048 + tid * 8) = lv;
      }
    }
    __syncthreads();

    bf16x8 fah[4], fal[4], fbh[4], fbl[4];
#pragma unroll
    for (int mi = 0; mi < 4; mi++) {
      int r = wm * 64 + mi * 16 + fr;
      fah[mi] = *(const bf16x8*)(sAh + r * 32 + fq * 8);
      fal[mi] = *(const bf16x8*)(sAl + r * 32 + fq * 8);
    }
#pragma unroll
    for (int ni = 0; ni < 4; ni++) {
      int c = wn * 64 + ni * 16 + fr;
      fbh[ni] = *(const bf16x8*)(sBh + c * 32 + fq * 8);
      fbl[ni] = *(const bf16x8*)(sBl + c * 32 + fq * 8);
    }
#pragma unroll
    for (int mi = 0; mi < 4; mi++)
#pragma unroll
      for (int ni = 0; ni < 4; ni++) {
        acc[mi][ni] = mfma16(fah[mi], fbh[ni], acc[mi][ni]);
        acc[mi][ni] = mfma16(fah[mi], fbl[ni], acc[mi][ni]);
        acc[mi][ni] = mfma16(fal[mi], fbh[ni], acc[mi][ni]);
      }
  }

#pragma unroll
  for (int mi = 0; mi < 4; mi++)
#pragma unroll
    for (int ni = 0; ni < 4; ni++)
#pragma unroll
      for (int rr = 0; rr < 4; rr++) {
        int row = rowBase + wm * 64 + mi * 16 + fq * 4 + rr;
        int col = colBase + wn * 64 + ni * 16 + fr;
        float v = acc[mi][ni][rr] + bias[col];
        if constexpr (MODE == 0) {
          int s = col >> 8, hl2 = (col >> 6) & 3, d = col & 63;
          int bn = row >> 7, t = row & 127;
          size_t idx;
          if (s == 2)
            idx = ((size_t)(bn * 4 + hl2) * 64 + d) * 128 + t;  // V^T [d][t]
          else
            idx = ((size_t)(bn * 4 + hl2) * 128 + t) * 64 + d;
          C[(size_t)s * 8388608 + idx] = v;
        } else {
          C[(size_t)row * 1024 + col] = v;
        }
      }
}

// ---------------------------------------------------------------------------
// MFMA attention, one block per (bn, head-in-group, 64-row Q half): 2048 blks.
// 3-term bf16 split for QK^T and PV; fp32 softmax (wave-private rows).
// LDS: sQ hi/lo (stride 72) 18K + sKV hi/lo half-buffer 18K + sS fp32
// (stride 132) 33K = 69 KB -> 2 blocks/CU. All frag reads 16B-aligned.
// ---------------------------------------------------------------------------
__global__ __launch_bounds__(256) void k_attn(
    const float* __restrict__ Q, const float* __restrict__ Kb,
    const float* __restrict__ Vt, const float* __restrict__ cosb,
    const float* __restrict__ absSp, unsigned short* __restrict__ Oh,
    unsigned short* __restrict__ Ol, int g) {
  __shared__ __align__(16) unsigned short sQ[2][64 * 72];
  __shared__ __align__(16) unsigned short sKV[2][64 * 72];
  __shared__ __align__(16) float sS[64 * 132];
  unsigned short* sP = (unsigned short*)sS;  // P hi/lo overwrites S in place

  int bx = blockIdx.x;
  int half = bx & 1, hl = (bx >> 1) & 3, bn = bx >> 3, b = bn >> 6;
  int tid = threadIdx.x, wave = tid >> 6, lane = tid & 63;
  int fr = lane & 15, fq = lane >> 4;
  size_t base = (size_t)(bn * 4 + hl) * 8192;
  float absS = absSp[0];

  // stage Q (rows half*64.., [t][d]) -> bf16 hi/lo
  {
    const float* src = Q + base + (size_t)half * 4096;
#pragma unroll
    for (int p = 0; p < 4; p++) {
      int f = p * 256 + tid, r = f >> 4, c = f & 15;
      float4 v = *(const float4*)(src + r * 64 + c * 4);
      ushort4 h, l;
      h.x = bfbits(v.x); l.x = bfbits(v.x - bff(h.x));
      h.y = bfbits(v.y); l.y = bfbits(v.y - bff(h.y));
      h.z = bfbits(v.z); l.z = bfbits(v.z - bff(h.z));
      h.w = bfbits(v.w); l.w = bfbits(v.w - bff(h.w));
      *(ushort4*)(&sQ[0][r * 72 + c * 4]) = h;
      *(ushort4*)(&sQ[1][r * 72 + c * 4]) = l;
    }
  }

  bf16x8 qh[2], ql[2];

  // ---- QK^T in two 64-col K halves --------------------------------------
#pragma unroll
  for (int kt = 0; kt < 2; kt++) {
    if (kt) __syncthreads();  // all waves done reading previous K half
    {
      const float* src = Kb + base + (size_t)kt * 4096;
#pragma unroll
      for (int p = 0; p < 4; p++) {
        int f = p * 256 + tid, r = f >> 4, c = f & 15;
        float4 v = *(const float4*)(src + r * 64 + c * 4);
        ushort4 h, l;
        h.x = bfbits(v.x); l.x = bfbits(v.x - bff(h.x));
        h.y = bfbits(v.y); l.y = bfbits(v.y - bff(h.y));
        h.z = bfbits(v.z); l.z = bfbits(v.z - bff(h.z));
        h.w = bfbits(v.w); l.w = bfbits(v.w - bff(h.w));
        *(ushort4*)(&sKV[0][r * 72 + c * 4]) = h;
        *(ushort4*)(&sKV[1][r * 72 + c * 4]) = l;
      }
    }
    __syncthreads();
    if (kt == 0) {
      int rowl = wave * 16 + fr;
#pragma unroll
      for (int ki = 0; ki < 2; ki++) {
        qh[ki] = *(const bf16x8*)(&sQ[0][rowl * 72 + ki * 32 + fq * 8]);
        ql[ki] = *(const bf16x8*)(&sQ[1][rowl * 72 + ki * 32 + fq * 8]);
      }
    }
#pragma unroll
    for (int nt = 0; nt < 4; nt++) {
      f32x4 a = (f32x4){0.f, 0.f, 0.f, 0.f};
      int cl = nt * 16 + fr;
#pragma unroll
      for (int ki = 0; ki < 2; ki++) {
        bf16x8 kh = *(const bf16x8*)(&sKV[0][cl * 72 + ki * 32 + fq * 8]);
        bf16x8 kl = *(const bf16x8*)(&sKV[1][cl * 72 + ki * 32 + fq * 8]);
        a = mfma16(qh[ki], kh, a);
        a = mfma16(qh[ki], kl, a);
        a = mfma16(ql[ki], kh, a);
      }
#pragma unroll
      for (int rr = 0; rr < 4; rr++) {
        int rl = wave * 16 + fq * 4 + rr;
        int col = kt * 64 + nt * 16 + fr;
        int tg = half * 64 + rl;
        float cv = cosb[((size_t)(b * 128 + tg)) * 128 + col];
        sS[rl * 132 + col] = a[rr] * 0.125f + absS * cv;
      }
    }
  }
  __syncthreads();  // all waves done reading sKV (K half 1)

  // stage V^T half 0 (overlaps softmax)
  {
    const float* src = Vt + base;
#pragma unroll
    for (int p = 0; p < 4; p++) {
      int f = p * 256 + tid, r = f >> 4, c = f & 15;
      float4 v = *(const float4*)(src + r * 128 + c * 4);
      ushort4 h, l;
      h.x = bfbits(v.x); l.x = bfbits(v.x - bff(h.x));
      h.y = bfbits(v.y); l.y = bfbits(v.y - bff(h.y));
      h.z = bfbits(v.z); l.z = bfbits(v.z - bff(h.z));
      h.w = bfbits(v.w); l.w = bfbits(v.w - bff(h.w));
      *(ushort4*)(&sKV[0][r * 72 + c * 4]) = h;
      *(ushort4*)(&sKV[1][r * 72 + c * 4]) = l;
    }
  }

  // ---- softmax: rows wave-private; write P bf16 hi/lo in place ----------
  for (int r = 0; r < 16; r++) {
    int tl = wave * 16 + r;
    float s0 = sS[tl * 132 + lane], s1 = sS[tl * 132 + 64 + lane];
    float m = fmaxf(s0, s1);
#pragma unroll
    for (int off = 32; off >= 1; off >>= 1) m = fmaxf(m, __shfl_xor(m, off));
    float p0 = __expf(s0 - m), p1 = __expf(s1 - m);
    float sum = p0 + p1;
#pragma unroll
    for (int off = 32; off >= 1; off >>= 1) sum += __shfl_xor(sum, off);
    float inv = 1.0f / sum;
    p0 *= inv; p1 *= inv;
    unsigned short h0 = bfbits(p0), h1 = bfbits(p1);
    sP[tl * 264 + lane] = h0;
    sP[tl * 264 + 64 + lane] = h1;
    sP[tl * 264 + 128 + lane] = bfbits(p0 - bff(h0));
    sP[tl * 264 + 192 + lane] = bfbits(p1 - bff(h1));
  }

  // ---- PV in two 64-t V halves ------------------------------------------
  f32x4 accO[4];
#pragma unroll
  for (int nt = 0; nt < 4; nt++) accO[nt] = (f32x4){0.f, 0.f, 0.f, 0.f};
#pragma unroll
  for (int vt = 0; vt < 2; vt++) {
    if (vt) {
      __syncthreads();  // all waves done reading V half 0
      const float* src = Vt + base + 64;
#pragma unroll
      for (int p = 0; p < 4; p++) {
        int f = p * 256 + tid, r = f >> 4, c = f & 15;
        float4 v = *(const float4*)(src + r * 128 + c * 4);
        ushort4 h, l;
        h.x = bfbits(v.x); l.x = bfbits(v.x - bff(h.x));
        h.y = bfbits(v.y); l.y = bfbits(v.y - bff(h.y));
        h.z = bfbits(v.z); l.z = bfbits(v.z - bff(h.z));
        h.w = bfbits(v.w); l.w = bfbits(v.w - bff(h.w));
        *(ushort4*)(&sKV[0][r * 72 + c * 4]) = h;
        *(ushort4*)(&sKV[1][r * 72 + c * 4]) = l;
      }
    }
    __syncthreads();  // V half staged
    int rowl = wave * 16 + fr;
    bf16x8 ph[2], pl[2];
#pragma unroll
    for (int ki = 0; ki < 2; ki++) {
      ph[ki] = *(const bf16x8*)(&sP[rowl * 264 + vt * 64 + ki * 32 + fq * 8]);
      pl[ki] = *(const bf16x8*)(&sP[rowl * 264 + 128 + vt * 64 + ki * 32 + fq * 8]);
    }
#pragma unroll
    for (int nt = 0; nt < 4; nt++) {
      int d = nt * 16 + fr;
#pragma unroll
      for (int ki = 0; ki < 2; ki++) {
        bf16x8 vh = *(const bf16x8*)(&sKV[0][d * 72 + ki * 32 + fq * 8]);
        bf16x8 vl = *(const bf16x8*)(&sKV[1][d * 72 + ki * 32 + fq * 8]);
        accO[nt] = mfma16(ph[ki], vh, accO[nt]);
        accO[nt] = mfma16(ph[ki], vl, accO[nt]);
        accO[nt] = mfma16(pl[ki], vh, accO[nt]);
      }
    }
  }

  // ---- epilogue: O -> global bf16 hi/lo ---------------------------------
  int hg = g * 4 + hl;
#pragma unroll
  for (int nt = 0; nt < 4; nt++)
#pragma unroll
    for (int rr = 0; rr < 4; rr++) {
      int tl = wave * 16 + fq * 4 + rr;
      int tg = half * 64 + tl;
      int d = nt * 16 + fr;
      float v = accO[nt][rr];
      size_t o = ((size_t)(bn * 128 + tg)) * 1024 + hg * 64 + d;
      unsigned short h = bfbits(v);
      Oh[o] = h;
      Ol[o] = bfbits(v - bff(h));
    }
}

// ---------------------------------------------------------------------------
extern "C" void kernel_launch(void* const* d_in, const int* in_sizes, int n_in,
                              void* d_out, int out_size, void* d_ws,
                              size_t ws_size, hipStream_t stream) {
  const float* x = (const float*)d_in[0];
  const float* bv = (const float*)d_in[1];
  const float* qkvw = (const float*)d_in[2];
  const float* qkvb = (const float*)d_in[3];
  const float* projw = (const float*)d_in[4];
  const float* projb = (const float*)d_in[5];
  const float* absS = (const float*)d_in[6];
  float* out = (float*)d_out;

  char* ws = (char*)d_ws;
  size_t off = 0;
  auto alloc = [&](size_t b) {
    char* p = ws + off;
    off += (b + 255) & ~(size_t)255;
    return p;
  };
  unsigned short* wqh = (unsigned short*)alloc((size_t)3072 * 1024 * 2);
  unsigned short* wql = (unsigned short*)alloc((size_t)3072 * 1024 * 2);
  unsigned short* wph = (unsigned short*)alloc((size_t)1024 * 1024 * 2);
  unsigned short* wpl = (unsigned short*)alloc((size_t)1024 * 1024 * 2);
  float* gbias = (float*)alloc(3072 * 4);
  float* cosb = (float*)alloc((size_t)4 * 128 * 128 * 4);
  unsigned short* Oh = (unsigned short*)alloc((size_t)MROWS * 1024 * 2);
  unsigned short* Ol = (unsigned short*)alloc((size_t)MROWS * 1024 * 2);
  unsigned short* xh = (unsigned short*)alloc((size_t)MROWS * 1024 * 2);
  unsigned short* xl = (unsigned short*)alloc((size_t)MROWS * 1024 * 2);
  bool planA = (off <= ws_size);

  float* qg = (float*)d_out;  // q +0, k +8388608, v^T +16777216 floats

  k_tsplit<<<dim3(96, 32), dim3(32, 8), 0, stream>>>(qkvw, wqh, wql, 1024, 3072, 1);
  k_tsplit<<<dim3(32, 32), dim3(32, 8), 0, stream>>>(projw, wph, wpl, 1024, 1024, 0);
  k_gbias<<<dim3(12), dim3(256), 0, stream>>>(qkvb, gbias);
  k_cos<<<dim3(4), dim3(128), 0, stream>>>(bv, cosb);
  if (planA)
    k_split<<<dim3(32768), dim3(256), 0, stream>>>(x, xh, xl, 8388608);

  for (int g = 0; g < 4; g++) {
    const unsigned short* bq = wqh + (size_t)g * 768 * 1024;
    const unsigned short* bl = wql + (size_t)g * 768 * 1024;
    if (planA)
      k_gemm<0, 0><<<dim3(256, 6), dim3(256), 0, stream>>>(
          xh, xl, nullptr, bq, bl, gbias + g * 768, qg);
    else
      k_gemm<1, 0><<<dim3(256, 6), dim3(256), 0, stream>>>(
          nullptr, nullptr, x, bq, bl, gbias + g * 768, qg);
    k_attn<<<dim3(2048), dim3(256), 0, stream>>>(
        qg, qg + 8388608, qg + 16777216, cosb, absS, Oh, Ol, g);
  }

  k_gemm<0, 1><<<dim3(256, 8), dim3(256), 0, stream>>>(
      Oh, Ol, nullptr, wph, wpl, projb, out);
}